// Round 3
// baseline (513.366 us; speedup 1.0000x reference)
//
#include <hip/hip_runtime.h>
#include <hip/hip_bf16.h>

typedef unsigned short u16;
typedef __attribute__((ext_vector_type(8))) short bf16x8;          // 8 x 16-bit payload regs
typedef __attribute__((ext_vector_type(8))) _Float16 f16x8;
typedef __attribute__((ext_vector_type(8))) unsigned short u16x8;
typedef __attribute__((ext_vector_type(4))) float f32x4;

// fp16 conversion (round-to-nearest-even). All 16-bit values in this pipeline
// are fp16 now: |x|<=6, |W|<=0.1, |q,k,v,c|<=8, P in [0,1] -- well inside range,
// and fp16's 11 mantissa bits cut rounding error 8x vs bf16 (same MFMA rate).
__device__ __forceinline__ u16 f2b(float f) {
  _Float16 h = (_Float16)f;
  return __builtin_bit_cast(u16, h);
}

__device__ __forceinline__ f32x4 mfma16(bf16x8 a, bf16x8 b, f32x4 c) {
  return __builtin_amdgcn_mfma_f32_16x16x32_f16(
      __builtin_bit_cast(f16x8, a), __builtin_bit_cast(f16x8, b), c, 0, 0, 0);
}

#define GLD16(dst, src) __builtin_amdgcn_global_load_lds( \
    (const __attribute__((address_space(1))) void*)(src), \
    (__attribute__((address_space(3))) void*)(dst), 16, 0, 0)

// ---------------------------------------------------------------------------
// pack_x: A1[n][k] f16, k<1024 from x_r, else x_i.  (n = b*2048+l token)
// ---------------------------------------------------------------------------
__global__ void pack_x_kernel(u16* __restrict__ A1, const float* __restrict__ xr,
                              const float* __restrict__ xi) {
  const int id = blockIdx.x * 256 + threadIdx.x;   // 1M threads, 8 elems each
  const size_t k8 = (size_t)id * 8;
  const int n = (int)(k8 >> 11);
  const int kk = (int)(k8 & 2047);
  const float* src = (kk < 1024) ? (xr + (size_t)n * 1024 + kk)
                                 : (xi + (size_t)n * 1024 + (kk - 1024));
  float4 a = *(const float4*)src;
  float4 c = *(const float4*)(src + 4);
  u16x8 o;
  o[0] = f2b(a.x); o[1] = f2b(a.y); o[2] = f2b(a.z); o[3] = f2b(a.w);
  o[4] = f2b(c.x); o[5] = f2b(c.y); o[6] = f2b(c.z); o[7] = f2b(c.w);
  *(u16x8*)(A1 + k8) = o;
}

// ---------------------------------------------------------------------------
// pack_w: one 1024x2048 slab of packed weights.
// real (isim=0): [ Wr | -Wi ], bias = br - bi
// imag (isim=1): [ Wi |  Wr ], bias = br + bi
// ---------------------------------------------------------------------------
__global__ void pack_w_kernel(u16* __restrict__ dst, float* __restrict__ biasDst,
                              const float* __restrict__ Wr, const float* __restrict__ Wi,
                              const float* __restrict__ br, const float* __restrict__ bi,
                              int isim) {
  const int row = blockIdx.x;          // 0..1023 output feature d
  const int kk = threadIdx.x * 8;      // 0..2040
  const int half = kk >> 10;
  const int kloc = kk & 1023;
  const float* W = (half == 0) ? (isim ? Wi : Wr) : (isim ? Wr : Wi);
  const float sgn = (half == 1 && !isim) ? -1.f : 1.f;
  const float* src = W + (size_t)row * 1024 + kloc;
  float4 a = *(const float4*)src;
  float4 c = *(const float4*)(src + 4);
  u16x8 o;
  o[0] = f2b(sgn * a.x); o[1] = f2b(sgn * a.y); o[2] = f2b(sgn * a.z); o[3] = f2b(sgn * a.w);
  o[4] = f2b(sgn * c.x); o[5] = f2b(sgn * c.y); o[6] = f2b(sgn * c.z); o[7] = f2b(sgn * c.w);
  *(u16x8*)(dst + (size_t)row * 2048 + kk) = o;
  if (threadIdx.x == 0)
    biasDst[row] = isim ? (br[row] + bi[row]) : (br[row] - bi[row]);
}

// ---------------------------------------------------------------------------
// GEMM: C[4096][N] = A[4096][2048] * B[N][2048]^T + bias[N]
// 128x128 block tile, 4 waves (2x2) of 64x64, BK=64, 16x16x32 f16 MFMA.
// LDS staged via global_load_lds(16B) with XOR chunk swizzle (slot s of row r
// holds global chunk s^(r&7)); reads apply the same involution.
// Output j -> matrix (j>>10) of [4096][1024], element [row][j&1023].
// ---------------------------------------------------------------------------
template<int OUT_F32>
__global__ __launch_bounds__(256) void gemm_bt(const u16* __restrict__ A,
                                               const u16* __restrict__ Bw,
                                               const float* __restrict__ bias,
                                               void* __restrict__ outp) {
  constexpr int K = 2048;
  __shared__ __align__(16) u16 As[128 * 64];
  __shared__ __align__(16) u16 Bs[128 * 64];
  const int tid = threadIdx.x;
  const int w = tid >> 6, l = tid & 63;
  const int l15 = l & 15, lhi = l >> 4;
  const int m0 = blockIdx.y * 128, n0 = blockIdx.x * 128;
  const int wm = w >> 1, wn = w & 1;
  f32x4 acc[4][4] = {};
  for (int kt = 0; kt < K; kt += 64) {
#pragma unroll
    for (int it = 0; it < 4; ++it) {
      const int grp = it * 4 + w;
      const int cl = grp * 64 + l;
      const int r = cl >> 3;
      const int g = (cl & 7) ^ (r & 7);
      GLD16(As + grp * 512, A + (size_t)(m0 + r) * K + kt + g * 8);
      GLD16(Bs + grp * 512, Bw + (size_t)(n0 + r) * K + kt + g * 8);
    }
    __syncthreads();
#pragma unroll
    for (int ks = 0; ks < 2; ++ks) {
      const int c = ks * 4 + lhi;
      bf16x8 af[4], bfr[4];
#pragma unroll
      for (int mf = 0; mf < 4; ++mf) {
        const int r = wm * 64 + mf * 16 + l15;
        af[mf] = *(const bf16x8*)&As[r * 64 + ((c ^ (r & 7)) << 3)];
      }
#pragma unroll
      for (int nf = 0; nf < 4; ++nf) {
        const int r = wn * 64 + nf * 16 + l15;
        bfr[nf] = *(const bf16x8*)&Bs[r * 64 + ((c ^ (r & 7)) << 3)];
      }
#pragma unroll
      for (int mf = 0; mf < 4; ++mf)
#pragma unroll
        for (int nf = 0; nf < 4; ++nf)
          acc[mf][nf] = mfma16(af[mf], bfr[nf], acc[mf][nf]);
    }
    __syncthreads();
  }
#pragma unroll
  for (int nf = 0; nf < 4; ++nf) {
    const int j = n0 + wn * 64 + nf * 16 + l15;
    const float bv = bias[j];
    const size_t obase = (size_t)(j >> 10) * (4096 * 1024) + (j & 1023);
#pragma unroll
    for (int mf = 0; mf < 4; ++mf) {
#pragma unroll
      for (int i = 0; i < 4; ++i) {
        const int row = m0 + wm * 64 + mf * 16 + lhi * 4 + i;
        const float v = acc[mf][nf][i] + bv;
        if constexpr (OUT_F32) ((float*)outp)[obase + (size_t)row * 1024] = v;
        else                   ((u16*)outp)[obase + (size_t)row * 1024] = f2b(v);
      }
    }
  }
}

// ---------------------------------------------------------------------------
// transpose_v: v (token-major [4096][1024] head slice) -> vt[bh][d][token]
// ---------------------------------------------------------------------------
__global__ void transpose_v_kernel(const u16* __restrict__ v, u16* __restrict__ vt) {
  __shared__ u16 tile[64 * 65];
  const int tt = blockIdx.x, bh = blockIdx.y, ri = blockIdx.z;
  const int b = bh >> 4, h = bh & 15;
  const size_t M1 = (size_t)4096 * 1024;
  const u16* src = v + (size_t)ri * M1;
  u16* dst = vt + (size_t)ri * 32 * 64 * 2048;
  const int t0 = tt * 64;
#pragma unroll
  for (int e = 0; e < 16; ++e) {
    const int id = e * 256 + threadIdx.x;
    const int row = id >> 6, col = id & 63;
    tile[row * 65 + col] = src[(size_t)(b * 2048 + t0 + row) * 1024 + h * 64 + col];
  }
  __syncthreads();
#pragma unroll
  for (int e = 0; e < 16; ++e) {
    const int id = e * 256 + threadIdx.x;
    const int d = id >> 6, tok = id & 63;
    dst[((size_t)bh * 64 + d) * 2048 + t0 + tok] = tile[tok * 65 + d];
  }
}

// ---------------------------------------------------------------------------
// Flash interference attention.
// grid (32 q-tiles, 32 bh). 4 waves x 16 q-rows. KV tile = 64 keys.
// score = (sr^2 + si^2)/64 + mask; online softmax; P via per-wave LDS strip
// (stride 72 to dodge bank conflicts); PV from transposed-V tiles.
// Writes A2[4096][2048] f16: c_r cols 0..1023, c_i cols 1024..2047.
// ---------------------------------------------------------------------------
__global__ __launch_bounds__(256) void attn_kernel(const u16* __restrict__ qkv,
                                                   const u16* __restrict__ vt,
                                                   const float* __restrict__ mask,
                                                   u16* __restrict__ A2) {
  __shared__ __align__(16) u16 Kr[64 * 64];
  __shared__ __align__(16) u16 Ki[64 * 64];
  __shared__ __align__(16) u16 Vr[64 * 64];
  __shared__ __align__(16) u16 Vi[64 * 64];
  __shared__ __align__(16) u16 Pl[4 * 16 * 72];
  const int tid = threadIdx.x, w = tid >> 6, l = tid & 63;
  const int l15 = l & 15, lhi = l >> 4;
  const int q0 = blockIdx.x * 64;
  const int bh = blockIdx.y;
  const int b = bh >> 4, h = bh & 15;
  const size_t M1 = (size_t)4096 * 1024;
  const u16* qr_b = qkv;
  const u16* qi_b = qkv + M1;
  const u16* kr_b = qkv + 2 * M1;
  const u16* ki_b = qkv + 3 * M1;
  const u16* vtr = vt;
  const u16* vti = vt + (size_t)32 * 64 * 2048;

  const size_t qrow = (size_t)(b * 2048 + q0 + w * 16 + l15) * 1024 + h * 64;
  bf16x8 qr[2], qi[2], qrn[2];
#pragma unroll
  for (int ks = 0; ks < 2; ++ks) {
    qr[ks] = *(const bf16x8*)&qr_b[qrow + ks * 32 + lhi * 8];
    qi[ks] = *(const bf16x8*)&qi_b[qrow + ks * 32 + lhi * 8];
    qrn[ks] = qr[ks] ^ (short)0x8000;   // -Qr (f16 sign flip)
  }
  float mrow[4], lrow[4];
  f32x4 o_r[4] = {}, o_i[4] = {};
#pragma unroll
  for (int i = 0; i < 4; ++i) { mrow[i] = -1e30f; lrow[i] = 0.f; }
  u16* Pw = Pl + w * (16 * 72);

  for (int kt = 0; kt < 32; ++kt) {
    const int k0 = kt * 64;
#pragma unroll
    for (int it = 0; it < 2; ++it) {
      const int grp = it * 4 + w;
      const int cl = grp * 64 + l;
      const int r = cl >> 3;
      const int g = (cl & 7) ^ (r & 7);
      const size_t krow = (size_t)(b * 2048 + k0 + r) * 1024 + h * 64 + g * 8;
      const size_t vrow = (size_t)(bh * 64 + r) * 2048 + k0 + g * 8;
      GLD16(Kr + grp * 512, kr_b + krow);
      GLD16(Ki + grp * 512, ki_b + krow);
      GLD16(Vr + grp * 512, vtr + vrow);
      GLD16(Vi + grp * 512, vti + vrow);
    }
    __syncthreads();
    // ---- scores: sr = Qr.Kr + Qi.Ki ; si = Qi.Kr - Qr.Ki ----
    f32x4 sr[4] = {}, si[4] = {};
#pragma unroll
    for (int nf = 0; nf < 4; ++nf) {
      const int krr = nf * 16 + l15;
      const int sw = krr & 7;
#pragma unroll
      for (int ks = 0; ks < 2; ++ks) {
        const int c = ks * 4 + lhi;
        const int off = krr * 64 + ((c ^ sw) << 3);
        bf16x8 kfr = *(const bf16x8*)&Kr[off];
        bf16x8 kfi = *(const bf16x8*)&Ki[off];
        sr[nf] = mfma16(qr[ks], kfr, sr[nf]);
        sr[nf] = mfma16(qi[ks], kfi, sr[nf]);
        si[nf] = mfma16(qi[ks], kfr, si[nf]);
        si[nf] = mfma16(qrn[ks], kfi, si[nf]);
      }
    }
    float t[4][4];
#pragma unroll
    for (int nf = 0; nf < 4; ++nf) {
      const float mk = mask[b * 2048 + k0 + nf * 16 + l15];
#pragma unroll
      for (int i = 0; i < 4; ++i)
        t[nf][i] = (sr[nf][i] * sr[nf][i] + si[nf][i] * si[nf][i]) * 0.015625f + mk;
    }
    // ---- online softmax (row = lhi*4+i, spread over 16 lanes) ----
    float scale[4];
#pragma unroll
    for (int i = 0; i < 4; ++i) {
      float v = fmaxf(fmaxf(t[0][i], t[1][i]), fmaxf(t[2][i], t[3][i]));
      v = fmaxf(v, __shfl_xor(v, 1, 64));
      v = fmaxf(v, __shfl_xor(v, 2, 64));
      v = fmaxf(v, __shfl_xor(v, 4, 64));
      v = fmaxf(v, __shfl_xor(v, 8, 64));
      const float mn = fmaxf(mrow[i], v);
      scale[i] = __expf(mrow[i] - mn);
      mrow[i] = mn;
    }
    float p[4][4], rs[4] = {0.f, 0.f, 0.f, 0.f};
#pragma unroll
    for (int nf = 0; nf < 4; ++nf)
#pragma unroll
      for (int i = 0; i < 4; ++i) {
        p[nf][i] = __expf(t[nf][i] - mrow[i]);
        rs[i] += p[nf][i];
      }
#pragma unroll
    for (int i = 0; i < 4; ++i) {
      float v = rs[i];
      v += __shfl_xor(v, 1, 64);
      v += __shfl_xor(v, 2, 64);
      v += __shfl_xor(v, 4, 64);
      v += __shfl_xor(v, 8, 64);
      lrow[i] = lrow[i] * scale[i] + v;
#pragma unroll
      for (int nf = 0; nf < 4; ++nf) { o_r[nf][i] *= scale[i]; o_i[nf][i] *= scale[i]; }
    }
    // ---- P -> LDS (D-layout -> A-layout repack), then PV ----
#pragma unroll
    for (int nf = 0; nf < 4; ++nf)
#pragma unroll
      for (int i = 0; i < 4; ++i)
        Pw[(lhi * 4 + i) * 72 + nf * 16 + l15] = f2b(p[nf][i]);
#pragma unroll
    for (int ks = 0; ks < 2; ++ks) {
      bf16x8 pa = *(const bf16x8*)&Pw[l15 * 72 + ks * 32 + lhi * 8];
      const int c = ks * 4 + lhi;
#pragma unroll
      for (int nf = 0; nf < 4; ++nf) {
        const int vr = nf * 16 + l15;
        const int off = vr * 64 + ((c ^ (vr & 7)) << 3);
        bf16x8 vfr = *(const bf16x8*)&Vr[off];
        bf16x8 vfi = *(const bf16x8*)&Vi[off];
        o_r[nf] = mfma16(pa, vfr, o_r[nf]);
        o_i[nf] = mfma16(pa, vfi, o_i[nf]);
      }
    }
    __syncthreads();
  }
  float inv[4];
#pragma unroll
  for (int i = 0; i < 4; ++i) inv[i] = 1.f / lrow[i];
  const int rowbase = b * 2048 + q0 + w * 16 + lhi * 4;
#pragma unroll
  for (int nf = 0; nf < 4; ++nf) {
    const int col = h * 64 + nf * 16 + l15;
#pragma unroll
    for (int i = 0; i < 4; ++i) {
      const size_t rw = (size_t)(rowbase + i) * 2048;
      A2[rw + col] = f2b(o_r[nf][i] * inv[i]);
      A2[rw + 1024 + col] = f2b(o_i[nf][i] * inv[i]);
    }
  }
}

// ---------------------------------------------------------------------------
extern "C" void kernel_launch(void* const* d_in, const int* in_sizes, int n_in,
                              void* d_out, int out_size, void* d_ws, size_t ws_size,
                              hipStream_t stream) {
  (void)in_sizes; (void)n_in; (void)out_size; (void)ws_size;
  const float* x_r  = (const float*)d_in[0];
  const float* x_i  = (const float*)d_in[1];
  const float* mask = (const float*)d_in[2];
  const float* Wq_r = (const float*)d_in[3];
  const float* bq_r = (const float*)d_in[4];
  const float* Wq_i = (const float*)d_in[5];
  const float* bq_i = (const float*)d_in[6];
  const float* Wk_r = (const float*)d_in[7];
  const float* bk_r = (const float*)d_in[8];
  const float* Wk_i = (const float*)d_in[9];
  const float* bk_i = (const float*)d_in[10];
  const float* Wv_r = (const float*)d_in[11];
  const float* bv_r = (const float*)d_in[12];
  const float* Wv_i = (const float*)d_in[13];
  const float* bv_i = (const float*)d_in[14];
  const float* Wo_r = (const float*)d_in[15];
  const float* bo_r = (const float*)d_in[16];
  const float* Wo_i = (const float*)d_in[17];
  const float* bo_i = (const float*)d_in[18];

  char* ws = (char*)d_ws;
  const size_t M1 = (size_t)4096 * 1024;
  u16* A    = (u16*)(ws);                         // 16 MB: A1, later A2
  u16* B1   = (u16*)(ws + (16u << 20));           // 24 MB packed QKV weights
  u16* vt   = (u16*)(ws + (16u << 20));           // 16 MB (reuses B1 after QKV GEMM)
  u16* B2   = (u16*)(ws + (32u << 20));           // 8 MB packed O weights
  u16* qkv  = (u16*)(ws + (40u << 20));           // 48 MB qr,qi,kr,ki,vr,vi
  float* bias1 = (float*)(ws + (88u << 20));             // 24 KB
  float* bias2 = (float*)(ws + (88u << 20) + (1u << 15)); // 8 KB

  pack_x_kernel<<<4096, 256, 0, stream>>>(A, x_r, x_i);
  pack_w_kernel<<<1024, 256, 0, stream>>>(B1 + 0 * (size_t)1024 * 2048, bias1 + 0,    Wq_r, Wq_i, bq_r, bq_i, 0);
  pack_w_kernel<<<1024, 256, 0, stream>>>(B1 + 1 * (size_t)1024 * 2048, bias1 + 1024, Wq_r, Wq_i, bq_r, bq_i, 1);
  pack_w_kernel<<<1024, 256, 0, stream>>>(B1 + 2 * (size_t)1024 * 2048, bias1 + 2048, Wk_r, Wk_i, bk_r, bk_i, 0);
  pack_w_kernel<<<1024, 256, 0, stream>>>(B1 + 3 * (size_t)1024 * 2048, bias1 + 3072, Wk_r, Wk_i, bk_r, bk_i, 1);
  pack_w_kernel<<<1024, 256, 0, stream>>>(B1 + 4 * (size_t)1024 * 2048, bias1 + 4096, Wv_r, Wv_i, bv_r, bv_i, 0);
  pack_w_kernel<<<1024, 256, 0, stream>>>(B1 + 5 * (size_t)1024 * 2048, bias1 + 5120, Wv_r, Wv_i, bv_r, bv_i, 1);

  gemm_bt<0><<<dim3(48, 32), 256, 0, stream>>>(A, B1, bias1, qkv);

  transpose_v_kernel<<<dim3(32, 32, 2), 256, 0, stream>>>(qkv + 4 * M1, vt);
  pack_w_kernel<<<1024, 256, 0, stream>>>(B2,                      bias2,        Wo_r, Wo_i, bo_r, bo_i, 0);
  pack_w_kernel<<<1024, 256, 0, stream>>>(B2 + (size_t)1024 * 2048, bias2 + 1024, Wo_r, Wo_i, bo_r, bo_i, 1);

  attn_kernel<<<dim3(32, 32), 256, 0, stream>>>(qkv, vt, mask, A);

  gemm_bt<1><<<dim3(16, 32), 256, 0, stream>>>(A, B2, bias2, d_out);
}

// Round 4
// 478.234 us; speedup vs baseline: 1.0735x; 1.0735x over previous
//
#include <hip/hip_runtime.h>
#include <hip/hip_bf16.h>

typedef unsigned short u16;
typedef __attribute__((ext_vector_type(8))) short bf16x8;          // 8 x 16-bit payload regs
typedef __attribute__((ext_vector_type(8))) _Float16 f16x8;
typedef __attribute__((ext_vector_type(8))) unsigned short u16x8;
typedef __attribute__((ext_vector_type(4))) float f32x4;

// fp16 conversion (round-to-nearest-even). All 16-bit values in this pipeline
// are fp16: |x|<=6, |W|<=0.1, |q,k,v,c|<=8, P in (0, e^8] -- inside range,
// and fp16's 11 mantissa bits cut rounding error 8x vs bf16 (same MFMA rate).
__device__ __forceinline__ u16 f2b(float f) {
  _Float16 h = (_Float16)f;
  return __builtin_bit_cast(u16, h);
}

__device__ __forceinline__ f32x4 mfma16(bf16x8 a, bf16x8 b, f32x4 c) {
  return __builtin_amdgcn_mfma_f32_16x16x32_f16(
      __builtin_bit_cast(f16x8, a), __builtin_bit_cast(f16x8, b), c, 0, 0, 0);
}

#define GLD16(dst, src) __builtin_amdgcn_global_load_lds( \
    (const __attribute__((address_space(1))) void*)(src), \
    (__attribute__((address_space(3))) void*)(dst), 16, 0, 0)

// ---------------------------------------------------------------------------
// pack_x: A1[n][k] f16, k<1024 from x_r, else x_i.  (n = b*2048+l token)
// ---------------------------------------------------------------------------
__global__ void pack_x_kernel(u16* __restrict__ A1, const float* __restrict__ xr,
                              const float* __restrict__ xi) {
  const int id = blockIdx.x * 256 + threadIdx.x;   // 1M threads, 8 elems each
  const size_t k8 = (size_t)id * 8;
  const int n = (int)(k8 >> 11);
  const int kk = (int)(k8 & 2047);
  const float* src = (kk < 1024) ? (xr + (size_t)n * 1024 + kk)
                                 : (xi + (size_t)n * 1024 + (kk - 1024));
  float4 a = *(const float4*)src;
  float4 c = *(const float4*)(src + 4);
  u16x8 o;
  o[0] = f2b(a.x); o[1] = f2b(a.y); o[2] = f2b(a.z); o[3] = f2b(a.w);
  o[4] = f2b(c.x); o[5] = f2b(c.y); o[6] = f2b(c.z); o[7] = f2b(c.w);
  *(u16x8*)(A1 + k8) = o;
}

// ---------------------------------------------------------------------------
// pack_w: one 1024x2048 slab of packed weights.
// real (isim=0): [ Wr | -Wi ], bias = br - bi
// imag (isim=1): [ Wi |  Wr ], bias = br + bi
// ---------------------------------------------------------------------------
__global__ void pack_w_kernel(u16* __restrict__ dst, float* __restrict__ biasDst,
                              const float* __restrict__ Wr, const float* __restrict__ Wi,
                              const float* __restrict__ br, const float* __restrict__ bi,
                              int isim) {
  const int row = blockIdx.x;          // 0..1023 output feature d
  const int kk = threadIdx.x * 8;      // 0..2040
  const int half = kk >> 10;
  const int kloc = kk & 1023;
  const float* W = (half == 0) ? (isim ? Wi : Wr) : (isim ? Wr : Wi);
  const float sgn = (half == 1 && !isim) ? -1.f : 1.f;
  const float* src = W + (size_t)row * 1024 + kloc;
  float4 a = *(const float4*)src;
  float4 c = *(const float4*)(src + 4);
  u16x8 o;
  o[0] = f2b(sgn * a.x); o[1] = f2b(sgn * a.y); o[2] = f2b(sgn * a.z); o[3] = f2b(sgn * a.w);
  o[4] = f2b(sgn * c.x); o[5] = f2b(sgn * c.y); o[6] = f2b(sgn * c.z); o[7] = f2b(sgn * c.w);
  *(u16x8*)(dst + (size_t)row * 2048 + kk) = o;
  if (threadIdx.x == 0)
    biasDst[row] = isim ? (br[row] + bi[row]) : (br[row] - bi[row]);
}

// ---------------------------------------------------------------------------
// GEMM: C[4096][N] = A[4096][2048] * B[N][2048]^T + bias[N]
// 128x128 block tile, 4 waves (2x2) of 64x64, BK=64, 16x16x32 f16 MFMA.
// LDS staged via global_load_lds(16B) with XOR chunk swizzle (slot s of row r
// holds global chunk s^(r&7)); reads apply the same involution.
// Output j -> matrix (j>>10) of [4096][1024], element [row][j&1023].
// ---------------------------------------------------------------------------
template<int OUT_F32>
__global__ __launch_bounds__(256) void gemm_bt(const u16* __restrict__ A,
                                               const u16* __restrict__ Bw,
                                               const float* __restrict__ bias,
                                               void* __restrict__ outp) {
  constexpr int K = 2048;
  __shared__ __align__(16) u16 As[128 * 64];
  __shared__ __align__(16) u16 Bs[128 * 64];
  const int tid = threadIdx.x;
  const int w = tid >> 6, l = tid & 63;
  const int l15 = l & 15, lhi = l >> 4;
  const int m0 = blockIdx.y * 128, n0 = blockIdx.x * 128;
  const int wm = w >> 1, wn = w & 1;
  f32x4 acc[4][4] = {};
  for (int kt = 0; kt < K; kt += 64) {
#pragma unroll
    for (int it = 0; it < 4; ++it) {
      const int grp = it * 4 + w;
      const int cl = grp * 64 + l;
      const int r = cl >> 3;
      const int g = (cl & 7) ^ (r & 7);
      GLD16(As + grp * 512, A + (size_t)(m0 + r) * K + kt + g * 8);
      GLD16(Bs + grp * 512, Bw + (size_t)(n0 + r) * K + kt + g * 8);
    }
    __syncthreads();
#pragma unroll
    for (int ks = 0; ks < 2; ++ks) {
      const int c = ks * 4 + lhi;
      bf16x8 af[4], bfr[4];
#pragma unroll
      for (int mf = 0; mf < 4; ++mf) {
        const int r = wm * 64 + mf * 16 + l15;
        af[mf] = *(const bf16x8*)&As[r * 64 + ((c ^ (r & 7)) << 3)];
      }
#pragma unroll
      for (int nf = 0; nf < 4; ++nf) {
        const int r = wn * 64 + nf * 16 + l15;
        bfr[nf] = *(const bf16x8*)&Bs[r * 64 + ((c ^ (r & 7)) << 3)];
      }
#pragma unroll
      for (int mf = 0; mf < 4; ++mf)
#pragma unroll
        for (int nf = 0; nf < 4; ++nf)
          acc[mf][nf] = mfma16(af[mf], bfr[nf], acc[mf][nf]);
    }
    __syncthreads();
  }
#pragma unroll
  for (int nf = 0; nf < 4; ++nf) {
    const int j = n0 + wn * 64 + nf * 16 + l15;
    const float bv = bias[j];
    const size_t obase = (size_t)(j >> 10) * (4096 * 1024) + (j & 1023);
#pragma unroll
    for (int mf = 0; mf < 4; ++mf) {
#pragma unroll
      for (int i = 0; i < 4; ++i) {
        const int row = m0 + wm * 64 + mf * 16 + lhi * 4 + i;
        const float v = acc[mf][nf][i] + bv;
        if constexpr (OUT_F32) ((float*)outp)[obase + (size_t)row * 1024] = v;
        else                   ((u16*)outp)[obase + (size_t)row * 1024] = f2b(v);
      }
    }
  }
}

// ---------------------------------------------------------------------------
// transpose_v: v (token-major [4096][1024] head slice) -> vt[bh][d][token]
// ---------------------------------------------------------------------------
__global__ void transpose_v_kernel(const u16* __restrict__ v, u16* __restrict__ vt) {
  __shared__ u16 tile[64 * 65];
  const int tt = blockIdx.x, bh = blockIdx.y, ri = blockIdx.z;
  const int b = bh >> 4, h = bh & 15;
  const size_t M1 = (size_t)4096 * 1024;
  const u16* src = v + (size_t)ri * M1;
  u16* dst = vt + (size_t)ri * 32 * 64 * 2048;
  const int t0 = tt * 64;
#pragma unroll
  for (int e = 0; e < 16; ++e) {
    const int id = e * 256 + threadIdx.x;
    const int row = id >> 6, col = id & 63;
    tile[row * 65 + col] = src[(size_t)(b * 2048 + t0 + row) * 1024 + h * 64 + col];
  }
  __syncthreads();
#pragma unroll
  for (int e = 0; e < 16; ++e) {
    const int id = e * 256 + threadIdx.x;
    const int d = id >> 6, tok = id & 63;
    dst[((size_t)bh * 64 + d) * 2048 + t0 + tok] = tile[tok * 65 + d];
  }
}

// ---------------------------------------------------------------------------
// Flash interference attention, round 4:
//  - KV double-buffered LDS (2 x 32KB), single barrier per tile, prefetch
//    issued right after the barrier so HBM/L2 latency hides under compute.
//  - defer-max (THR=8): skip o/sum rescale unless a row's tile-max grew >8;
//    P bounded by e^8 (f16-safe).
//  - per-lane partial row sums, shfl-reduced ONCE at the end.
//  - setprio(1) around MFMA clusters.
// grid (32 q-tiles, 32 bh). 4 waves x 16 q-rows. KV tile = 64 keys.
// Writes A2[4096][2048] f16: c_r cols 0..1023, c_i cols 1024..2047.
// ---------------------------------------------------------------------------
__global__ __launch_bounds__(256) void attn_kernel(const u16* __restrict__ qkv,
                                                   const u16* __restrict__ vt,
                                                   const float* __restrict__ mask,
                                                   u16* __restrict__ A2) {
  __shared__ __align__(16) u16 KVb[2][4][64 * 64];  // [buf][Kr,Ki,Vr,Vi]
  __shared__ __align__(16) u16 Pl[4 * 16 * 72];
  const int tid = threadIdx.x, w = tid >> 6, l = tid & 63;
  const int l15 = l & 15, lhi = l >> 4;
  const int q0 = blockIdx.x * 64;
  const int bh = blockIdx.y;
  const int b = bh >> 4, h = bh & 15;
  const size_t M1 = (size_t)4096 * 1024;
  const u16* qr_b = qkv;
  const u16* qi_b = qkv + M1;
  const u16* kr_b = qkv + 2 * M1;
  const u16* ki_b = qkv + 3 * M1;
  const u16* vtr = vt;
  const u16* vti = vt + (size_t)32 * 64 * 2048;

  const size_t qrow = (size_t)(b * 2048 + q0 + w * 16 + l15) * 1024 + h * 64;
  bf16x8 qr[2], qi[2], qrn[2];
#pragma unroll
  for (int ks = 0; ks < 2; ++ks) {
    qr[ks] = *(const bf16x8*)&qr_b[qrow + ks * 32 + lhi * 8];
    qi[ks] = *(const bf16x8*)&qi_b[qrow + ks * 32 + lhi * 8];
    qrn[ks] = qr[ks] ^ (short)0x8000;   // -Qr (f16 sign flip)
  }
  float mrow[4], srow[4];
  f32x4 o_r[4] = {}, o_i[4] = {};
#pragma unroll
  for (int i = 0; i < 4; ++i) { mrow[i] = -1e30f; srow[i] = 0.f; }
  u16* Pw = Pl + w * (16 * 72);

  auto STAGE = [&](int tile, int bufi) {
    const int k0s = tile * 64;
#pragma unroll
    for (int it = 0; it < 2; ++it) {
      const int grp = it * 4 + w;
      const int cl = grp * 64 + l;
      const int r = cl >> 3;
      const int g = (cl & 7) ^ (r & 7);
      const size_t krow = (size_t)(b * 2048 + k0s + r) * 1024 + h * 64 + g * 8;
      const size_t vrow = (size_t)(bh * 64 + r) * 2048 + k0s + g * 8;
      GLD16(&KVb[bufi][0][grp * 512], kr_b + krow);
      GLD16(&KVb[bufi][1][grp * 512], ki_b + krow);
      GLD16(&KVb[bufi][2][grp * 512], vtr + vrow);
      GLD16(&KVb[bufi][3][grp * 512], vti + vrow);
    }
  };

  STAGE(0, 0);
  for (int kt = 0; kt < 32; ++kt) {
    const int cur = kt & 1;
    const int k0 = kt * 64;
    __syncthreads();               // implicit vmcnt(0): buf[cur] ready, waves aligned
    if (kt < 31) STAGE(kt + 1, cur ^ 1);   // prefetch overlaps this tile's compute
    const u16* Kr = &KVb[cur][0][0];
    const u16* Ki = &KVb[cur][1][0];
    const u16* Vr = &KVb[cur][2][0];
    const u16* Vi = &KVb[cur][3][0];
    // ---- scores: sr = Qr.Kr + Qi.Ki ; si = Qi.Kr - Qr.Ki ----
    f32x4 sr[4] = {}, si[4] = {};
    __builtin_amdgcn_s_setprio(1);
#pragma unroll
    for (int nf = 0; nf < 4; ++nf) {
      const int krr = nf * 16 + l15;
      const int sw = krr & 7;
#pragma unroll
      for (int ks = 0; ks < 2; ++ks) {
        const int c = ks * 4 + lhi;
        const int off = krr * 64 + ((c ^ sw) << 3);
        bf16x8 kfr = *(const bf16x8*)&Kr[off];
        bf16x8 kfi = *(const bf16x8*)&Ki[off];
        sr[nf] = mfma16(qr[ks], kfr, sr[nf]);
        sr[nf] = mfma16(qi[ks], kfi, sr[nf]);
        si[nf] = mfma16(qi[ks], kfr, si[nf]);
        si[nf] = mfma16(qrn[ks], kfi, si[nf]);
      }
    }
    __builtin_amdgcn_s_setprio(0);
    float t[4][4];
#pragma unroll
    for (int nf = 0; nf < 4; ++nf) {
      const float mk = mask[b * 2048 + k0 + nf * 16 + l15];
#pragma unroll
      for (int i = 0; i < 4; ++i)
        t[nf][i] = (sr[nf][i] * sr[nf][i] + si[nf][i] * si[nf][i]) * 0.015625f + mk;
    }
    // ---- per-tile row max (16-lane groups share a row set) ----
    float pmax[4];
#pragma unroll
    for (int i = 0; i < 4; ++i) {
      float v = fmaxf(fmaxf(t[0][i], t[1][i]), fmaxf(t[2][i], t[3][i]));
      v = fmaxf(v, __shfl_xor(v, 1, 64));
      v = fmaxf(v, __shfl_xor(v, 2, 64));
      v = fmaxf(v, __shfl_xor(v, 4, 64));
      v = fmaxf(v, __shfl_xor(v, 8, 64));
      pmax[i] = v;
    }
    // ---- defer-max: rescale only when some row grew > 8 ----
    bool grow = false;
#pragma unroll
    for (int i = 0; i < 4; ++i) grow |= (pmax[i] > mrow[i] + 8.f);
    if (__any(grow)) {
#pragma unroll
      for (int i = 0; i < 4; ++i) {
        const float mn = fmaxf(mrow[i], pmax[i]);
        const float sc = __expf(mrow[i] - mn);   // ==1.0 exactly when no growth
        mrow[i] = mn;
        srow[i] *= sc;
#pragma unroll
        for (int nf = 0; nf < 4; ++nf) { o_r[nf][i] *= sc; o_i[nf][i] *= sc; }
      }
    }
    float p[4][4];
#pragma unroll
    for (int nf = 0; nf < 4; ++nf)
#pragma unroll
      for (int i = 0; i < 4; ++i) {
        p[nf][i] = __expf(t[nf][i] - mrow[i]);   // bounded by e^8
        srow[i] += p[nf][i];
      }
    // ---- P -> LDS (D-layout -> A-layout repack), then PV ----
#pragma unroll
    for (int nf = 0; nf < 4; ++nf)
#pragma unroll
      for (int i = 0; i < 4; ++i)
        Pw[(lhi * 4 + i) * 72 + nf * 16 + l15] = f2b(p[nf][i]);
    __builtin_amdgcn_s_setprio(1);
#pragma unroll
    for (int ks = 0; ks < 2; ++ks) {
      bf16x8 pa = *(const bf16x8*)&Pw[l15 * 72 + ks * 32 + lhi * 8];
      const int c = ks * 4 + lhi;
#pragma unroll
      for (int nf = 0; nf < 4; ++nf) {
        const int vr = nf * 16 + l15;
        const int off = vr * 64 + ((c ^ (vr & 7)) << 3);
        bf16x8 vfr = *(const bf16x8*)&Vr[off];
        bf16x8 vfi = *(const bf16x8*)&Vi[off];
        o_r[nf] = mfma16(pa, vfr, o_r[nf]);
        o_i[nf] = mfma16(pa, vfi, o_i[nf]);
      }
    }
    __builtin_amdgcn_s_setprio(0);
  }
  // ---- final row-sum reduce (once) + normalize + store ----
  float inv[4];
#pragma unroll
  for (int i = 0; i < 4; ++i) {
    float v = srow[i];
    v += __shfl_xor(v, 1, 64);
    v += __shfl_xor(v, 2, 64);
    v += __shfl_xor(v, 4, 64);
    v += __shfl_xor(v, 8, 64);
    inv[i] = 1.f / v;
  }
  const int rowbase = b * 2048 + q0 + w * 16 + lhi * 4;
#pragma unroll
  for (int nf = 0; nf < 4; ++nf) {
    const int col = h * 64 + nf * 16 + l15;
#pragma unroll
    for (int i = 0; i < 4; ++i) {
      const size_t rw = (size_t)(rowbase + i) * 2048;
      A2[rw + col] = f2b(o_r[nf][i] * inv[i]);
      A2[rw + 1024 + col] = f2b(o_i[nf][i] * inv[i]);
    }
  }
}

// ---------------------------------------------------------------------------
extern "C" void kernel_launch(void* const* d_in, const int* in_sizes, int n_in,
                              void* d_out, int out_size, void* d_ws, size_t ws_size,
                              hipStream_t stream) {
  (void)in_sizes; (void)n_in; (void)out_size; (void)ws_size;
  const float* x_r  = (const float*)d_in[0];
  const float* x_i  = (const float*)d_in[1];
  const float* mask = (const float*)d_in[2];
  const float* Wq_r = (const float*)d_in[3];
  const float* bq_r = (const float*)d_in[4];
  const float* Wq_i = (const float*)d_in[5];
  const float* bq_i = (const float*)d_in[6];
  const float* Wk_r = (const float*)d_in[7];
  const float* bk_r = (const float*)d_in[8];
  const float* Wk_i = (const float*)d_in[9];
  const float* bk_i = (const float*)d_in[10];
  const float* Wv_r = (const float*)d_in[11];
  const float* bv_r = (const float*)d_in[12];
  const float* Wv_i = (const float*)d_in[13];
  const float* bv_i = (const float*)d_in[14];
  const float* Wo_r = (const float*)d_in[15];
  const float* bo_r = (const float*)d_in[16];
  const float* Wo_i = (const float*)d_in[17];
  const float* bo_i = (const float*)d_in[18];

  char* ws = (char*)d_ws;
  const size_t M1 = (size_t)4096 * 1024;
  u16* A    = (u16*)(ws);                         // 16 MB: A1, later A2
  u16* B1   = (u16*)(ws + (16u << 20));           // 24 MB packed QKV weights
  u16* vt   = (u16*)(ws + (16u << 20));           // 16 MB (reuses B1 after QKV GEMM)
  u16* B2   = (u16*)(ws + (32u << 20));           // 8 MB packed O weights
  u16* qkv  = (u16*)(ws + (40u << 20));           // 48 MB qr,qi,kr,ki,vr,vi
  float* bias1 = (float*)(ws + (88u << 20));             // 24 KB
  float* bias2 = (float*)(ws + (88u << 20) + (1u << 15)); // 8 KB

  pack_x_kernel<<<4096, 256, 0, stream>>>(A, x_r, x_i);
  pack_w_kernel<<<1024, 256, 0, stream>>>(B1 + 0 * (size_t)1024 * 2048, bias1 + 0,    Wq_r, Wq_i, bq_r, bq_i, 0);
  pack_w_kernel<<<1024, 256, 0, stream>>>(B1 + 1 * (size_t)1024 * 2048, bias1 + 1024, Wq_r, Wq_i, bq_r, bq_i, 1);
  pack_w_kernel<<<1024, 256, 0, stream>>>(B1 + 2 * (size_t)1024 * 2048, bias1 + 2048, Wk_r, Wk_i, bk_r, bk_i, 0);
  pack_w_kernel<<<1024, 256, 0, stream>>>(B1 + 3 * (size_t)1024 * 2048, bias1 + 3072, Wk_r, Wk_i, bk_r, bk_i, 1);
  pack_w_kernel<<<1024, 256, 0, stream>>>(B1 + 4 * (size_t)1024 * 2048, bias1 + 4096, Wv_r, Wv_i, bv_r, bv_i, 0);
  pack_w_kernel<<<1024, 256, 0, stream>>>(B1 + 5 * (size_t)1024 * 2048, bias1 + 5120, Wv_r, Wv_i, bv_r, bv_i, 1);

  gemm_bt<0><<<dim3(48, 32), 256, 0, stream>>>(A, B1, bias1, qkv);

  transpose_v_kernel<<<dim3(32, 32, 2), 256, 0, stream>>>(qkv + 4 * M1, vt);
  pack_w_kernel<<<1024, 256, 0, stream>>>(B2,                      bias2,        Wo_r, Wo_i, bo_r, bo_i, 0);
  pack_w_kernel<<<1024, 256, 0, stream>>>(B2 + (size_t)1024 * 2048, bias2 + 1024, Wo_r, Wo_i, bo_r, bo_i, 1);

  attn_kernel<<<dim3(32, 32), 256, 0, stream>>>(qkv, vt, mask, A);

  gemm_bt<1><<<dim3(16, 32), 256, 0, stream>>>(A, B2, bias2, d_out);
}